// Round 5
// baseline (3213.837 us; speedup 1.0000x reference)
//
#include <hip/hip_runtime.h>
#include <cstdint>

#define NN 50000
#define NE 640000

// ---------------- CSR build ----------------

__global__ void hist_kernel(const int* __restrict__ dst, int* __restrict__ cnt) {
    int i = blockIdx.x * 256 + threadIdx.x;
    if (i < NE) atomicAdd(&cnt[dst[i]], 1);
}

// exclusive scan, 256-element blocks (Hillis-Steele in LDS)
__global__ void scan_block(const int* __restrict__ in, int* __restrict__ out,
                           int* __restrict__ partials, int n) {
    __shared__ int sm[256];
    int t = threadIdx.x;
    int gid = blockIdx.x * 256 + t;
    int v = (gid < n) ? in[gid] : 0;
    sm[t] = v;
    __syncthreads();
#pragma unroll
    for (int off = 1; off < 256; off <<= 1) {
        int add = (t >= off) ? sm[t - off] : 0;
        __syncthreads();
        sm[t] += add;
        __syncthreads();
    }
    if (gid < n) out[gid] = sm[t] - v;            // exclusive
    if (t == 255) partials[blockIdx.x] = sm[255];
}

__global__ void scan_partials(int* __restrict__ p, int nb) {
    __shared__ int sm[256];
    int t = threadIdx.x;
    int v = (t < nb) ? p[t] : 0;
    sm[t] = v;
    __syncthreads();
#pragma unroll
    for (int off = 1; off < 256; off <<= 1) {
        int add = (t >= off) ? sm[t - off] : 0;
        __syncthreads();
        sm[t] += add;
        __syncthreads();
    }
    if (t < nb) p[t] = sm[t] - v;                 // exclusive
}

// finalize offsets + init cursors + compute dinv (fused)
__global__ void finalize_offsets(int* __restrict__ offs, const int* __restrict__ partials,
                                 int* __restrict__ cursor, const int* __restrict__ cnt,
                                 float* __restrict__ dinv, int n) {
    int gid = blockIdx.x * 256 + threadIdx.x;
    if (gid < n) {
        int v = offs[gid] + partials[blockIdx.x];
        offs[gid] = v;
        cursor[gid] = v;
        dinv[gid] = rsqrtf((float)cnt[gid] + 1.0f);   // +1 for self-loop
    }
}

// packed CSR entry: {src, norm as bits} -> single 8B store / load
__global__ void csr_fill(const int* __restrict__ ei, const float* __restrict__ dinv,
                         int* __restrict__ cursor, int2* __restrict__ csr) {
    int e = blockIdx.x * 256 + threadIdx.x;
    if (e < NE) {
        int s = ei[e], d = ei[NE + e];
        int pos = atomicAdd(&cursor[d], 1);
        csr[pos] = make_int2(s, __float_as_int(dinv[s] * dinv[d]));
    }
}

// ---------------- fp32 GEMM, K=128 fixed, 64x64 tile ----------------
// B panel in LDS (32KB); A read straight from global (16-lane broadcast per row,
// each A element fetched once per block). Register-double-buffered A prefetch.

__global__ __launch_bounds__(256) void gemm_k128(const float* __restrict__ A,
                                                 const float* __restrict__ B,
                                                 float* __restrict__ C,
                                                 int M, int N) {
    __shared__ __align__(16) float Bs[128][64];
    const int t  = threadIdx.x;
    const int m0 = blockIdx.x * 64;
    const int n0 = blockIdx.y * 64;

    // load B panel (128 x 64 cols), zero-fill past N
#pragma unroll
    for (int i = 0; i < 8; ++i) {
        int idx = i * 256 + t;
        int k = idx >> 4, c4 = idx & 15;
        int gn = n0 + c4 * 4;
        float4 v;
        v.x = (gn + 0 < N) ? B[k * N + gn + 0] : 0.f;
        v.y = (gn + 1 < N) ? B[k * N + gn + 1] : 0.f;
        v.z = (gn + 2 < N) ? B[k * N + gn + 2] : 0.f;
        v.w = (gn + 3 < N) ? B[k * N + gn + 3] : 0.f;
        *reinterpret_cast<float4*>(&Bs[k][c4 * 4]) = v;
    }
    __syncthreads();

    const int tx = t & 15, ty = t >> 4;
    const float* Ap0 = A + (size_t)min(m0 + ty * 4 + 0, M - 1) * 128;
    const float* Ap1 = A + (size_t)min(m0 + ty * 4 + 1, M - 1) * 128;
    const float* Ap2 = A + (size_t)min(m0 + ty * 4 + 2, M - 1) * 128;
    const float* Ap3 = A + (size_t)min(m0 + ty * 4 + 3, M - 1) * 128;

    float acc[4][4] = {};
    float4 c0 = *reinterpret_cast<const float4*>(Ap0);
    float4 c1 = *reinterpret_cast<const float4*>(Ap1);
    float4 c2 = *reinterpret_cast<const float4*>(Ap2);
    float4 c3 = *reinterpret_cast<const float4*>(Ap3);

#pragma unroll
    for (int it = 0; it < 32; ++it) {
        float4 p0 = c0, p1 = c1, p2 = c2, p3 = c3;
        if (it < 31) {
            c0 = *reinterpret_cast<const float4*>(Ap0 + (it + 1) * 4);
            c1 = *reinterpret_cast<const float4*>(Ap1 + (it + 1) * 4);
            c2 = *reinterpret_cast<const float4*>(Ap2 + (it + 1) * 4);
            c3 = *reinterpret_cast<const float4*>(Ap3 + (it + 1) * 4);
        }
        float a0[4] = {p0.x, p0.y, p0.z, p0.w};
        float a1[4] = {p1.x, p1.y, p1.z, p1.w};
        float a2[4] = {p2.x, p2.y, p2.z, p2.w};
        float a3[4] = {p3.x, p3.y, p3.z, p3.w};
#pragma unroll
        for (int kk = 0; kk < 4; ++kk) {
            float4 b = *reinterpret_cast<const float4*>(&Bs[it * 4 + kk][tx * 4]);
            acc[0][0] += a0[kk] * b.x; acc[0][1] += a0[kk] * b.y; acc[0][2] += a0[kk] * b.z; acc[0][3] += a0[kk] * b.w;
            acc[1][0] += a1[kk] * b.x; acc[1][1] += a1[kk] * b.y; acc[1][2] += a1[kk] * b.z; acc[1][3] += a1[kk] * b.w;
            acc[2][0] += a2[kk] * b.x; acc[2][1] += a2[kk] * b.y; acc[2][2] += a2[kk] * b.z; acc[2][3] += a2[kk] * b.w;
            acc[3][0] += a3[kk] * b.x; acc[3][1] += a3[kk] * b.y; acc[3][2] += a3[kk] * b.z; acc[3][3] += a3[kk] * b.w;
        }
    }

#pragma unroll
    for (int i = 0; i < 4; ++i) {
        int gm = m0 + ty * 4 + i;
        if (gm >= M) continue;
        int gn = n0 + tx * 4;
        if (gn + 3 < N) {
            *reinterpret_cast<float4*>(&C[(size_t)gm * N + gn]) =
                make_float4(acc[i][0], acc[i][1], acc[i][2], acc[i][3]);
        } else {
#pragma unroll
            for (int j = 0; j < 4; ++j)
                if (gn + j < N) C[(size_t)gm * N + gn + j] = acc[i][j];
        }
    }
}

// ---------------- gather layer 1 (128 ch) + fused self-loop/bias/ReLU ----------------
// one dst node per 32 lanes, lane owns a float4 of channels; edge loop unrolled x4

__global__ __launch_bounds__(256) void gather128(const int* __restrict__ offs,
                                                 const int* __restrict__ ends,
                                                 const int2* __restrict__ csr,
                                                 const float* __restrict__ H1,
                                                 const float* __restrict__ dinv,
                                                 const float* __restrict__ b1,
                                                 float* __restrict__ h) {
    const int c = (threadIdx.x & 31) * 4;
    const int n = (blockIdx.x * 256 + threadIdx.x) >> 5;    // grid exact: NN*32 threads
    const int beg = offs[n], end = ends[n];
    float4 acc = make_float4(0.f, 0.f, 0.f, 0.f);
    int j = beg;
    const int n4end = beg + ((end - beg) & ~3);
    for (; j < n4end; j += 4) {
        int2 p0 = csr[j + 0], p1 = csr[j + 1], p2 = csr[j + 2], p3 = csr[j + 3];
        float4 v0 = *reinterpret_cast<const float4*>(H1 + (size_t)p0.x * 128 + c);
        float4 v1 = *reinterpret_cast<const float4*>(H1 + (size_t)p1.x * 128 + c);
        float4 v2 = *reinterpret_cast<const float4*>(H1 + (size_t)p2.x * 128 + c);
        float4 v3 = *reinterpret_cast<const float4*>(H1 + (size_t)p3.x * 128 + c);
        float w0 = __int_as_float(p0.y), w1 = __int_as_float(p1.y);
        float w2 = __int_as_float(p2.y), w3 = __int_as_float(p3.y);
        acc.x += v0.x * w0 + v1.x * w1 + v2.x * w2 + v3.x * w3;
        acc.y += v0.y * w0 + v1.y * w1 + v2.y * w2 + v3.y * w3;
        acc.z += v0.z * w0 + v1.z * w1 + v2.z * w2 + v3.z * w3;
        acc.w += v0.w * w0 + v1.w * w1 + v2.w * w2 + v3.w * w3;
    }
    for (; j < end; ++j) {
        int2 p = csr[j];
        float w = __int_as_float(p.y);
        float4 v = *reinterpret_cast<const float4*>(H1 + (size_t)p.x * 128 + c);
        acc.x += v.x * w; acc.y += v.y * w; acc.z += v.z * w; acc.w += v.w * w;
    }
    float di = dinv[n];
    float sl = di * di;
    float4 sv = *reinterpret_cast<const float4*>(H1 + (size_t)n * 128 + c);
    float4 bv = *reinterpret_cast<const float4*>(b1 + c);
    float4 r;
    r.x = fmaxf(fmaf(sv.x, sl, acc.x + bv.x), 0.f);
    r.y = fmaxf(fmaf(sv.y, sl, acc.y + bv.y), 0.f);
    r.z = fmaxf(fmaf(sv.z, sl, acc.z + bv.z), 0.f);
    r.w = fmaxf(fmaf(sv.w, sl, acc.w + bv.w), 0.f);
    *reinterpret_cast<float4*>(h + (size_t)n * 128 + c) = r;
}

// ---------------- gather layer 2 (40 ch) + fused self-loop/bias ----------------
// one dst node per 10 lanes, lane owns a float4 of channels; edge loop unrolled x4

__global__ __launch_bounds__(256) void gather40(const int* __restrict__ offs,
                                                const int* __restrict__ ends,
                                                const int2* __restrict__ csr,
                                                const float* __restrict__ H2,
                                                const float* __restrict__ dinv,
                                                const float* __restrict__ b2,
                                                float* __restrict__ out) {
    int idx = blockIdx.x * 256 + threadIdx.x;
    if (idx >= NN * 10) return;
    const int n = idx / 10;
    const int c = (idx - n * 10) * 4;
    const int beg = offs[n], end = ends[n];
    float4 acc = make_float4(0.f, 0.f, 0.f, 0.f);
    int j = beg;
    const int n4end = beg + ((end - beg) & ~3);
    for (; j < n4end; j += 4) {
        int2 p0 = csr[j + 0], p1 = csr[j + 1], p2 = csr[j + 2], p3 = csr[j + 3];
        float4 v0 = *reinterpret_cast<const float4*>(H2 + (size_t)p0.x * 40 + c);
        float4 v1 = *reinterpret_cast<const float4*>(H2 + (size_t)p1.x * 40 + c);
        float4 v2 = *reinterpret_cast<const float4*>(H2 + (size_t)p2.x * 40 + c);
        float4 v3 = *reinterpret_cast<const float4*>(H2 + (size_t)p3.x * 40 + c);
        float w0 = __int_as_float(p0.y), w1 = __int_as_float(p1.y);
        float w2 = __int_as_float(p2.y), w3 = __int_as_float(p3.y);
        acc.x += v0.x * w0 + v1.x * w1 + v2.x * w2 + v3.x * w3;
        acc.y += v0.y * w0 + v1.y * w1 + v2.y * w2 + v3.y * w3;
        acc.z += v0.z * w0 + v1.z * w1 + v2.z * w2 + v3.z * w3;
        acc.w += v0.w * w0 + v1.w * w1 + v2.w * w2 + v3.w * w3;
    }
    for (; j < end; ++j) {
        int2 p = csr[j];
        float w = __int_as_float(p.y);
        float4 v = *reinterpret_cast<const float4*>(H2 + (size_t)p.x * 40 + c);
        acc.x += v.x * w; acc.y += v.y * w; acc.z += v.z * w; acc.w += v.w * w;
    }
    float di = dinv[n];
    float sl = di * di;
    float4 sv = *reinterpret_cast<const float4*>(H2 + (size_t)n * 40 + c);
    float4 bv = *reinterpret_cast<const float4*>(b2 + c);
    float4 r;
    r.x = fmaf(sv.x, sl, acc.x + bv.x);
    r.y = fmaf(sv.y, sl, acc.y + bv.y);
    r.z = fmaf(sv.z, sl, acc.z + bv.z);
    r.w = fmaf(sv.w, sl, acc.w + bv.w);
    *reinterpret_cast<float4*>(out + (size_t)n * 40 + c) = r;
}

// ---------------- launch ----------------

extern "C" void kernel_launch(void* const* d_in, const int* in_sizes, int n_in,
                              void* d_out, int out_size, void* d_ws, size_t ws_size,
                              hipStream_t stream) {
    const float* x  = (const float*)d_in[0];
    const int*   ei = (const int*)d_in[1];     // [2, NE]: row0 = src, row1 = dst
    const float* W1 = (const float*)d_in[2];
    const float* b1 = (const float*)d_in[3];
    const float* W2 = (const float*)d_in[4];
    const float* b2 = (const float*)d_in[5];
    float* out = (float*)d_out;

    // workspace layout (4B elements)
    int*   deg_i    = (int*)d_ws;                  // [50048]
    float* dinv     = (float*)d_ws + 50048;        // [50048]
    int*   offs     = (int*)d_ws + 100096;         // [50048]
    int*   cursor   = (int*)d_ws + 150144;         // [50048] -> ends after csr_fill
    int*   partials = (int*)d_ws + 200192;         // [512]
    int2*  csr      = (int2*)((int*)d_ws + 200704);// [640000] packed {src, norm}
    float* H1       = (float*)d_ws + 1480704;      // [6400000] (reused as H2 later)
    float* h        = (float*)d_ws + 7880704;      // [6400000]
    float* H2       = H1;                          // alias: H1 dead after gather128

    const int NB = (NN + 255) / 256;               // 196 scan blocks

    // CSR build
    hipMemsetAsync(deg_i, 0, NN * sizeof(int), stream);
    hist_kernel<<<(NE + 255) / 256, 256, 0, stream>>>(ei + NE, deg_i);
    scan_block<<<NB, 256, 0, stream>>>(deg_i, offs, partials, NN);
    scan_partials<<<1, 256, 0, stream>>>(partials, NB);
    finalize_offsets<<<NB, 256, 0, stream>>>(offs, partials, cursor, deg_i, dinv, NN);
    csr_fill<<<(NE + 255) / 256, 256, 0, stream>>>(ei, dinv, cursor, csr);

    // layer 1
    gemm_k128<<<dim3((NN + 63) / 64, 2), 256, 0, stream>>>(x, W1, H1, NN, 128);
    gather128<<<NN * 32 / 256, 256, 0, stream>>>(offs, cursor, csr, H1, dinv, b1, h);

    // layer 2
    gemm_k128<<<dim3((NN + 63) / 64, 1), 256, 0, stream>>>(h, W2, H2, NN, 40);
    gather40<<<(NN * 10 + 255) / 256, 256, 0, stream>>>(offs, cursor, csr, H2, dinv, b2, out);
}

// Round 6
// 265.004 us; speedup vs baseline: 12.1275x; 12.1275x over previous
//
#include <hip/hip_runtime.h>
#include <cstdint>

#define NN 50000
#define NE 640000

// ---------------- CSR build ----------------

__global__ void hist_kernel(const int* __restrict__ dst, int* __restrict__ cnt) {
    int i = blockIdx.x * 256 + threadIdx.x;
    if (i < NE) atomicAdd(&cnt[dst[i]], 1);
}

// exclusive scan, 256-element blocks (Hillis-Steele in LDS)
__global__ void scan_block(const int* __restrict__ in, int* __restrict__ out,
                           int* __restrict__ partials, int n) {
    __shared__ int sm[256];
    int t = threadIdx.x;
    int gid = blockIdx.x * 256 + t;
    int v = (gid < n) ? in[gid] : 0;
    sm[t] = v;
    __syncthreads();
#pragma unroll
    for (int off = 1; off < 256; off <<= 1) {
        int add = (t >= off) ? sm[t - off] : 0;
        __syncthreads();
        sm[t] += add;
        __syncthreads();
    }
    if (gid < n) out[gid] = sm[t] - v;            // exclusive
    if (t == 255) partials[blockIdx.x] = sm[255];
}

__global__ void scan_partials(int* __restrict__ p, int nb) {
    __shared__ int sm[256];
    int t = threadIdx.x;
    int v = (t < nb) ? p[t] : 0;
    sm[t] = v;
    __syncthreads();
#pragma unroll
    for (int off = 1; off < 256; off <<= 1) {
        int add = (t >= off) ? sm[t - off] : 0;
        __syncthreads();
        sm[t] += add;
        __syncthreads();
    }
    if (t < nb) p[t] = sm[t] - v;                 // exclusive
}

// finalize offsets + init cursors + compute dinv (fused)
__global__ void finalize_offsets(int* __restrict__ offs, const int* __restrict__ partials,
                                 int* __restrict__ cursor, const int* __restrict__ cnt,
                                 float* __restrict__ dinv, int n) {
    int gid = blockIdx.x * 256 + threadIdx.x;
    if (gid < n) {
        int v = offs[gid] + partials[blockIdx.x];
        offs[gid] = v;
        cursor[gid] = v;
        dinv[gid] = rsqrtf((float)cnt[gid] + 1.0f);   // +1 for self-loop
    }
}

// packed CSR entry: {src, norm as bits} -> single 8B store / load
__global__ void csr_fill(const int* __restrict__ ei, const float* __restrict__ dinv,
                         int* __restrict__ cursor, int2* __restrict__ csr) {
    int e = blockIdx.x * 256 + threadIdx.x;
    if (e < NE) {
        int s = ei[e], d = ei[NE + e];
        int pos = atomicAdd(&cursor[d], 1);
        csr[pos] = make_int2(s, __float_as_int(dinv[s] * dinv[d]));
    }
}

// ---------------- fp32 GEMM, K=128 (two 64-wide steps), 64x64 tile ----------------
// Both tiles in LDS, 33.8 KB total -> 4 blocks/CU. Proven round-3 structure,
// halved LDS via K-split. (Round-5 lesson: register-prefetch A spills -> 66x traffic.)

__global__ __launch_bounds__(256) void gemm_k128(const float* __restrict__ A,
                                                 const float* __restrict__ B,
                                                 float* __restrict__ C,
                                                 int M, int N) {
    __shared__ float As[64][68];                  // +4 pad: 2-way bank alias only (free)
    __shared__ __align__(16) float Bs[64][64];
    const int t  = threadIdx.x;
    const int m0 = blockIdx.x * 64;
    const int n0 = blockIdx.y * 64;
    const int tx = t & 15, ty = t >> 4;

    float acc[4][4] = {};

    for (int ks = 0; ks < 2; ++ks) {
        // A tile: 64 rows x 64 cols (cols ks*64 .. ks*64+63), coalesced float4
#pragma unroll
        for (int i = 0; i < 4; ++i) {
            int idx = i * 256 + t;
            int r = idx >> 4, c4 = idx & 15;
            int gm = m0 + r;
            float4 v = make_float4(0.f, 0.f, 0.f, 0.f);
            if (gm < M) v = *reinterpret_cast<const float4*>(&A[(size_t)gm * 128 + ks * 64 + c4 * 4]);
            As[r][c4 * 4 + 0] = v.x;
            As[r][c4 * 4 + 1] = v.y;
            As[r][c4 * 4 + 2] = v.z;
            As[r][c4 * 4 + 3] = v.w;
        }
        // B tile: 64 k-rows x 64 cols, zero-fill past N
#pragma unroll
        for (int i = 0; i < 4; ++i) {
            int idx = i * 256 + t;
            int k = idx >> 4, c4 = idx & 15;
            int gk = ks * 64 + k;
            int gn = n0 + c4 * 4;
            float4 v;
            v.x = (gn + 0 < N) ? B[(size_t)gk * N + gn + 0] : 0.f;
            v.y = (gn + 1 < N) ? B[(size_t)gk * N + gn + 1] : 0.f;
            v.z = (gn + 2 < N) ? B[(size_t)gk * N + gn + 2] : 0.f;
            v.w = (gn + 3 < N) ? B[(size_t)gk * N + gn + 3] : 0.f;
            *reinterpret_cast<float4*>(&Bs[k][c4 * 4]) = v;
        }
        __syncthreads();

#pragma unroll 8
        for (int k = 0; k < 64; ++k) {
            float a0 = As[ty * 4 + 0][k];
            float a1 = As[ty * 4 + 1][k];
            float a2 = As[ty * 4 + 2][k];
            float a3 = As[ty * 4 + 3][k];
            float4 b = *reinterpret_cast<const float4*>(&Bs[k][tx * 4]);
            acc[0][0] += a0 * b.x; acc[0][1] += a0 * b.y; acc[0][2] += a0 * b.z; acc[0][3] += a0 * b.w;
            acc[1][0] += a1 * b.x; acc[1][1] += a1 * b.y; acc[1][2] += a1 * b.z; acc[1][3] += a1 * b.w;
            acc[2][0] += a2 * b.x; acc[2][1] += a2 * b.y; acc[2][2] += a2 * b.z; acc[2][3] += a2 * b.w;
            acc[3][0] += a3 * b.x; acc[3][1] += a3 * b.y; acc[3][2] += a3 * b.z; acc[3][3] += a3 * b.w;
        }
        __syncthreads();
    }

#pragma unroll
    for (int i = 0; i < 4; ++i) {
        int gm = m0 + ty * 4 + i;
        if (gm >= M) continue;
        int gn = n0 + tx * 4;
        if (gn + 3 < N) {
            *reinterpret_cast<float4*>(&C[(size_t)gm * N + gn]) =
                make_float4(acc[i][0], acc[i][1], acc[i][2], acc[i][3]);
        } else {
#pragma unroll
            for (int j = 0; j < 4; ++j)
                if (gn + j < N) C[(size_t)gm * N + gn + j] = acc[i][j];
        }
    }
}

// ---------------- gather layer 1 (128 ch) + fused self-loop/bias/ReLU ----------------
// one dst node per 32 lanes, lane owns a float4 of channels; edge loop unrolled x4

__global__ __launch_bounds__(256) void gather128(const int* __restrict__ offs,
                                                 const int* __restrict__ ends,
                                                 const int2* __restrict__ csr,
                                                 const float* __restrict__ H1,
                                                 const float* __restrict__ dinv,
                                                 const float* __restrict__ b1,
                                                 float* __restrict__ h) {
    const int c = (threadIdx.x & 31) * 4;
    const int n = (blockIdx.x * 256 + threadIdx.x) >> 5;    // grid exact: NN*32 threads
    const int beg = offs[n], end = ends[n];
    float4 acc = make_float4(0.f, 0.f, 0.f, 0.f);
    int j = beg;
    const int n4end = beg + ((end - beg) & ~3);
    for (; j < n4end; j += 4) {
        int2 p0 = csr[j + 0], p1 = csr[j + 1], p2 = csr[j + 2], p3 = csr[j + 3];
        float4 v0 = *reinterpret_cast<const float4*>(H1 + (size_t)p0.x * 128 + c);
        float4 v1 = *reinterpret_cast<const float4*>(H1 + (size_t)p1.x * 128 + c);
        float4 v2 = *reinterpret_cast<const float4*>(H1 + (size_t)p2.x * 128 + c);
        float4 v3 = *reinterpret_cast<const float4*>(H1 + (size_t)p3.x * 128 + c);
        float w0 = __int_as_float(p0.y), w1 = __int_as_float(p1.y);
        float w2 = __int_as_float(p2.y), w3 = __int_as_float(p3.y);
        acc.x += v0.x * w0 + v1.x * w1 + v2.x * w2 + v3.x * w3;
        acc.y += v0.y * w0 + v1.y * w1 + v2.y * w2 + v3.y * w3;
        acc.z += v0.z * w0 + v1.z * w1 + v2.z * w2 + v3.z * w3;
        acc.w += v0.w * w0 + v1.w * w1 + v2.w * w2 + v3.w * w3;
    }
    for (; j < end; ++j) {
        int2 p = csr[j];
        float w = __int_as_float(p.y);
        float4 v = *reinterpret_cast<const float4*>(H1 + (size_t)p.x * 128 + c);
        acc.x += v.x * w; acc.y += v.y * w; acc.z += v.z * w; acc.w += v.w * w;
    }
    float di = dinv[n];
    float sl = di * di;
    float4 sv = *reinterpret_cast<const float4*>(H1 + (size_t)n * 128 + c);
    float4 bv = *reinterpret_cast<const float4*>(b1 + c);
    float4 r;
    r.x = fmaxf(fmaf(sv.x, sl, acc.x + bv.x), 0.f);
    r.y = fmaxf(fmaf(sv.y, sl, acc.y + bv.y), 0.f);
    r.z = fmaxf(fmaf(sv.z, sl, acc.z + bv.z), 0.f);
    r.w = fmaxf(fmaf(sv.w, sl, acc.w + bv.w), 0.f);
    *reinterpret_cast<float4*>(h + (size_t)n * 128 + c) = r;
}

// ---------------- gather layer 2 (40 ch) + fused self-loop/bias ----------------
// one dst node per 10 lanes, lane owns a float4 of channels; edge loop unrolled x4

__global__ __launch_bounds__(256) void gather40(const int* __restrict__ offs,
                                                const int* __restrict__ ends,
                                                const int2* __restrict__ csr,
                                                const float* __restrict__ H2,
                                                const float* __restrict__ dinv,
                                                const float* __restrict__ b2,
                                                float* __restrict__ out) {
    int idx = blockIdx.x * 256 + threadIdx.x;
    if (idx >= NN * 10) return;
    const int n = idx / 10;
    const int c = (idx - n * 10) * 4;
    const int beg = offs[n], end = ends[n];
    float4 acc = make_float4(0.f, 0.f, 0.f, 0.f);
    int j = beg;
    const int n4end = beg + ((end - beg) & ~3);
    for (; j < n4end; j += 4) {
        int2 p0 = csr[j + 0], p1 = csr[j + 1], p2 = csr[j + 2], p3 = csr[j + 3];
        float4 v0 = *reinterpret_cast<const float4*>(H2 + (size_t)p0.x * 40 + c);
        float4 v1 = *reinterpret_cast<const float4*>(H2 + (size_t)p1.x * 40 + c);
        float4 v2 = *reinterpret_cast<const float4*>(H2 + (size_t)p2.x * 40 + c);
        float4 v3 = *reinterpret_cast<const float4*>(H2 + (size_t)p3.x * 40 + c);
        float w0 = __int_as_float(p0.y), w1 = __int_as_float(p1.y);
        float w2 = __int_as_float(p2.y), w3 = __int_as_float(p3.y);
        acc.x += v0.x * w0 + v1.x * w1 + v2.x * w2 + v3.x * w3;
        acc.y += v0.y * w0 + v1.y * w1 + v2.y * w2 + v3.y * w3;
        acc.z += v0.z * w0 + v1.z * w1 + v2.z * w2 + v3.z * w3;
        acc.w += v0.w * w0 + v1.w * w1 + v2.w * w2 + v3.w * w3;
    }
    for (; j < end; ++j) {
        int2 p = csr[j];
        float w = __int_as_float(p.y);
        float4 v = *reinterpret_cast<const float4*>(H2 + (size_t)p.x * 40 + c);
        acc.x += v.x * w; acc.y += v.y * w; acc.z += v.z * w; acc.w += v.w * w;
    }
    float di = dinv[n];
    float sl = di * di;
    float4 sv = *reinterpret_cast<const float4*>(H2 + (size_t)n * 40 + c);
    float4 bv = *reinterpret_cast<const float4*>(b2 + c);
    float4 r;
    r.x = fmaf(sv.x, sl, acc.x + bv.x);
    r.y = fmaf(sv.y, sl, acc.y + bv.y);
    r.z = fmaf(sv.z, sl, acc.z + bv.z);
    r.w = fmaf(sv.w, sl, acc.w + bv.w);
    *reinterpret_cast<float4*>(out + (size_t)n * 40 + c) = r;
}

// ---------------- launch ----------------

extern "C" void kernel_launch(void* const* d_in, const int* in_sizes, int n_in,
                              void* d_out, int out_size, void* d_ws, size_t ws_size,
                              hipStream_t stream) {
    const float* x  = (const float*)d_in[0];
    const int*   ei = (const int*)d_in[1];     // [2, NE]: row0 = src, row1 = dst
    const float* W1 = (const float*)d_in[2];
    const float* b1 = (const float*)d_in[3];
    const float* W2 = (const float*)d_in[4];
    const float* b2 = (const float*)d_in[5];
    float* out = (float*)d_out;

    // workspace layout (4B elements)
    int*   deg_i    = (int*)d_ws;                  // [50048]
    float* dinv     = (float*)d_ws + 50048;        // [50048]
    int*   offs     = (int*)d_ws + 100096;         // [50048]
    int*   cursor   = (int*)d_ws + 150144;         // [50048] -> ends after csr_fill
    int*   partials = (int*)d_ws + 200192;         // [512]
    int2*  csr      = (int2*)((int*)d_ws + 200704);// [640000] packed {src, norm}
    float* H1       = (float*)d_ws + 1480704;      // [6400000] (reused as H2 later)
    float* h        = (float*)d_ws + 7880704;      // [6400000]
    float* H2       = H1;                          // alias: H1 dead after gather128

    const int NB = (NN + 255) / 256;               // 196 scan blocks

    // CSR build
    hipMemsetAsync(deg_i, 0, NN * sizeof(int), stream);
    hist_kernel<<<(NE + 255) / 256, 256, 0, stream>>>(ei + NE, deg_i);
    scan_block<<<NB, 256, 0, stream>>>(deg_i, offs, partials, NN);
    scan_partials<<<1, 256, 0, stream>>>(partials, NB);
    finalize_offsets<<<NB, 256, 0, stream>>>(offs, partials, cursor, deg_i, dinv, NN);
    csr_fill<<<(NE + 255) / 256, 256, 0, stream>>>(ei, dinv, cursor, csr);

    // layer 1
    gemm_k128<<<dim3((NN + 63) / 64, 2), 256, 0, stream>>>(x, W1, H1, NN, 128);
    gather128<<<NN * 32 / 256, 256, 0, stream>>>(offs, cursor, csr, H1, dinv, b1, h);

    // layer 2
    gemm_k128<<<dim3((NN + 63) / 64, 1), 256, 0, stream>>>(h, W2, H2, NN, 40);
    gather40<<<(NN * 10 + 255) / 256, 256, 0, stream>>>(offs, cursor, csr, H2, dinv, b2, out);
}

// Round 7
// 243.644 us; speedup vs baseline: 13.1907x; 1.0877x over previous
//
#include <hip/hip_runtime.h>
#include <cstdint>

#define NN 50000
#define NE 640000

typedef unsigned short ushort_t;

__device__ __forceinline__ ushort_t f2bf(float f) {
    unsigned int b = __float_as_uint(f);
    return (ushort_t)((b + 0x7FFF + ((b >> 16) & 1)) >> 16);   // RNE
}
__device__ __forceinline__ float bf2f(ushort_t u) {
    return __uint_as_float(((unsigned int)u) << 16);
}

// ---------------- CSR build ----------------

__global__ void hist_kernel(const int* __restrict__ dst, int* __restrict__ cnt) {
    int i = blockIdx.x * 256 + threadIdx.x;
    if (i < NE) atomicAdd(&cnt[dst[i]], 1);
}

// exclusive scan, 256-element blocks (Hillis-Steele in LDS)
__global__ void scan_block(const int* __restrict__ in, int* __restrict__ out,
                           int* __restrict__ partials, int n) {
    __shared__ int sm[256];
    int t = threadIdx.x;
    int gid = blockIdx.x * 256 + t;
    int v = (gid < n) ? in[gid] : 0;
    sm[t] = v;
    __syncthreads();
#pragma unroll
    for (int off = 1; off < 256; off <<= 1) {
        int add = (t >= off) ? sm[t - off] : 0;
        __syncthreads();
        sm[t] += add;
        __syncthreads();
    }
    if (gid < n) out[gid] = sm[t] - v;            // exclusive
    if (t == 255) partials[blockIdx.x] = sm[255];
}

__global__ void scan_partials(int* __restrict__ p, int nb) {
    __shared__ int sm[256];
    int t = threadIdx.x;
    int v = (t < nb) ? p[t] : 0;
    sm[t] = v;
    __syncthreads();
#pragma unroll
    for (int off = 1; off < 256; off <<= 1) {
        int add = (t >= off) ? sm[t - off] : 0;
        __syncthreads();
        sm[t] += add;
        __syncthreads();
    }
    if (t < nb) p[t] = sm[t] - v;                 // exclusive
}

// finalize offsets + init cursors + compute dinv (fused)
__global__ void finalize_offsets(int* __restrict__ offs, const int* __restrict__ partials,
                                 int* __restrict__ cursor, const int* __restrict__ cnt,
                                 float* __restrict__ dinv, int n) {
    int gid = blockIdx.x * 256 + threadIdx.x;
    if (gid < n) {
        int v = offs[gid] + partials[blockIdx.x];
        offs[gid] = v;
        cursor[gid] = v;
        dinv[gid] = rsqrtf((float)cnt[gid] + 1.0f);   // +1 for self-loop
    }
}

// packed CSR entry: {src, norm as bits} -> single 8B store / load
__global__ void csr_fill(const int* __restrict__ ei, const float* __restrict__ dinv,
                         int* __restrict__ cursor, int2* __restrict__ csr) {
    int e = blockIdx.x * 256 + threadIdx.x;
    if (e < NE) {
        int s = ei[e], d = ei[NE + e];
        int pos = atomicAdd(&cursor[d], 1);
        csr[pos] = make_int2(s, __float_as_int(dinv[s] * dinv[d]));
    }
}

// ---------------- fp32 GEMM, K=128 (two 64-wide steps), 64x64 tile ----------------
// fp32 compute; output stored as bf16 (halves gather-side bytes).
// Round-5 lesson: register-prefetch A spills; keep LDS tiles (33.8 KB -> 4 blocks/CU).

__global__ __launch_bounds__(256) void gemm_k128_bf16out(const float* __restrict__ A,
                                                         const float* __restrict__ B,
                                                         ushort_t* __restrict__ C,
                                                         int M, int N) {
    __shared__ float As[64][68];                  // +4 pad: 2-way bank alias only (free)
    __shared__ __align__(16) float Bs[64][64];
    const int t  = threadIdx.x;
    const int m0 = blockIdx.x * 64;
    const int n0 = blockIdx.y * 64;
    const int tx = t & 15, ty = t >> 4;

    float acc[4][4] = {};

    for (int ks = 0; ks < 2; ++ks) {
#pragma unroll
        for (int i = 0; i < 4; ++i) {
            int idx = i * 256 + t;
            int r = idx >> 4, c4 = idx & 15;
            int gm = m0 + r;
            float4 v = make_float4(0.f, 0.f, 0.f, 0.f);
            if (gm < M) v = *reinterpret_cast<const float4*>(&A[(size_t)gm * 128 + ks * 64 + c4 * 4]);
            As[r][c4 * 4 + 0] = v.x;
            As[r][c4 * 4 + 1] = v.y;
            As[r][c4 * 4 + 2] = v.z;
            As[r][c4 * 4 + 3] = v.w;
        }
#pragma unroll
        for (int i = 0; i < 4; ++i) {
            int idx = i * 256 + t;
            int k = idx >> 4, c4 = idx & 15;
            int gk = ks * 64 + k;
            int gn = n0 + c4 * 4;
            float4 v;
            v.x = (gn + 0 < N) ? B[(size_t)gk * N + gn + 0] : 0.f;
            v.y = (gn + 1 < N) ? B[(size_t)gk * N + gn + 1] : 0.f;
            v.z = (gn + 2 < N) ? B[(size_t)gk * N + gn + 2] : 0.f;
            v.w = (gn + 3 < N) ? B[(size_t)gk * N + gn + 3] : 0.f;
            *reinterpret_cast<float4*>(&Bs[k][c4 * 4]) = v;
        }
        __syncthreads();

#pragma unroll 8
        for (int k = 0; k < 64; ++k) {
            float a0 = As[ty * 4 + 0][k];
            float a1 = As[ty * 4 + 1][k];
            float a2 = As[ty * 4 + 2][k];
            float a3 = As[ty * 4 + 3][k];
            float4 b = *reinterpret_cast<const float4*>(&Bs[k][tx * 4]);
            acc[0][0] += a0 * b.x; acc[0][1] += a0 * b.y; acc[0][2] += a0 * b.z; acc[0][3] += a0 * b.w;
            acc[1][0] += a1 * b.x; acc[1][1] += a1 * b.y; acc[1][2] += a1 * b.z; acc[1][3] += a1 * b.w;
            acc[2][0] += a2 * b.x; acc[2][1] += a2 * b.y; acc[2][2] += a2 * b.z; acc[2][3] += a2 * b.w;
            acc[3][0] += a3 * b.x; acc[3][1] += a3 * b.y; acc[3][2] += a3 * b.z; acc[3][3] += a3 * b.w;
        }
        __syncthreads();
    }

#pragma unroll
    for (int i = 0; i < 4; ++i) {
        int gm = m0 + ty * 4 + i;
        if (gm >= M) continue;
        int gn = n0 + tx * 4;
        if (gn + 3 < N) {
            ushort4 o;
            o.x = f2bf(acc[i][0]); o.y = f2bf(acc[i][1]);
            o.z = f2bf(acc[i][2]); o.w = f2bf(acc[i][3]);
            *reinterpret_cast<ushort4*>(&C[(size_t)gm * N + gn]) = o;   // 8B aligned (gn%4==0)
        } else {
#pragma unroll
            for (int j = 0; j < 4; ++j)
                if (gn + j < N) C[(size_t)gm * N + gn + j] = f2bf(acc[i][j]);
        }
    }
}

// ---------------- gather layer 1 (128 ch bf16) + fused self-loop/bias/ReLU ----------------
// one dst node per 32 lanes, lane owns 4 channels (ushort4 = 8B); edge loop unrolled x4

__global__ __launch_bounds__(256) void gather128(const int* __restrict__ offs,
                                                 const int* __restrict__ ends,
                                                 const int2* __restrict__ csr,
                                                 const ushort_t* __restrict__ H1,
                                                 const float* __restrict__ dinv,
                                                 const float* __restrict__ b1,
                                                 float* __restrict__ h) {
    const int c = (threadIdx.x & 31) * 4;
    const int n = (blockIdx.x * 256 + threadIdx.x) >> 5;    // grid exact: NN*32 threads
    const int beg = offs[n], end = ends[n];
    float4 acc = make_float4(0.f, 0.f, 0.f, 0.f);
    int j = beg;
    const int n4end = beg + ((end - beg) & ~3);
    for (; j < n4end; j += 4) {
        int2 p0 = csr[j + 0], p1 = csr[j + 1], p2 = csr[j + 2], p3 = csr[j + 3];
        ushort4 v0 = *reinterpret_cast<const ushort4*>(H1 + (size_t)p0.x * 128 + c);
        ushort4 v1 = *reinterpret_cast<const ushort4*>(H1 + (size_t)p1.x * 128 + c);
        ushort4 v2 = *reinterpret_cast<const ushort4*>(H1 + (size_t)p2.x * 128 + c);
        ushort4 v3 = *reinterpret_cast<const ushort4*>(H1 + (size_t)p3.x * 128 + c);
        float w0 = __int_as_float(p0.y), w1 = __int_as_float(p1.y);
        float w2 = __int_as_float(p2.y), w3 = __int_as_float(p3.y);
        acc.x += bf2f(v0.x) * w0 + bf2f(v1.x) * w1 + bf2f(v2.x) * w2 + bf2f(v3.x) * w3;
        acc.y += bf2f(v0.y) * w0 + bf2f(v1.y) * w1 + bf2f(v2.y) * w2 + bf2f(v3.y) * w3;
        acc.z += bf2f(v0.z) * w0 + bf2f(v1.z) * w1 + bf2f(v2.z) * w2 + bf2f(v3.z) * w3;
        acc.w += bf2f(v0.w) * w0 + bf2f(v1.w) * w1 + bf2f(v2.w) * w2 + bf2f(v3.w) * w3;
    }
    for (; j < end; ++j) {
        int2 p = csr[j];
        float w = __int_as_float(p.y);
        ushort4 v = *reinterpret_cast<const ushort4*>(H1 + (size_t)p.x * 128 + c);
        acc.x += bf2f(v.x) * w; acc.y += bf2f(v.y) * w;
        acc.z += bf2f(v.z) * w; acc.w += bf2f(v.w) * w;
    }
    float di = dinv[n];
    float sl = di * di;
    ushort4 sv = *reinterpret_cast<const ushort4*>(H1 + (size_t)n * 128 + c);
    float4 bv = *reinterpret_cast<const float4*>(b1 + c);
    float4 r;
    r.x = fmaxf(fmaf(bf2f(sv.x), sl, acc.x + bv.x), 0.f);
    r.y = fmaxf(fmaf(bf2f(sv.y), sl, acc.y + bv.y), 0.f);
    r.z = fmaxf(fmaf(bf2f(sv.z), sl, acc.z + bv.z), 0.f);
    r.w = fmaxf(fmaf(bf2f(sv.w), sl, acc.w + bv.w), 0.f);
    *reinterpret_cast<float4*>(h + (size_t)n * 128 + c) = r;
}

// ---------------- gather layer 2 (40 ch bf16) + fused self-loop/bias ----------------
// one dst node per 10 lanes, lane owns 4 channels (ushort4); edge loop unrolled x4

__global__ __launch_bounds__(256) void gather40(const int* __restrict__ offs,
                                                const int* __restrict__ ends,
                                                const int2* __restrict__ csr,
                                                const ushort_t* __restrict__ H2,
                                                const float* __restrict__ dinv,
                                                const float* __restrict__ b2,
                                                float* __restrict__ out) {
    int idx = blockIdx.x * 256 + threadIdx.x;
    if (idx >= NN * 10) return;
    const int n = idx / 10;
    const int c = (idx - n * 10) * 4;
    const int beg = offs[n], end = ends[n];
    float4 acc = make_float4(0.f, 0.f, 0.f, 0.f);
    int j = beg;
    const int n4end = beg + ((end - beg) & ~3);
    for (; j < n4end; j += 4) {
        int2 p0 = csr[j + 0], p1 = csr[j + 1], p2 = csr[j + 2], p3 = csr[j + 3];
        ushort4 v0 = *reinterpret_cast<const ushort4*>(H2 + (size_t)p0.x * 40 + c);
        ushort4 v1 = *reinterpret_cast<const ushort4*>(H2 + (size_t)p1.x * 40 + c);
        ushort4 v2 = *reinterpret_cast<const ushort4*>(H2 + (size_t)p2.x * 40 + c);
        ushort4 v3 = *reinterpret_cast<const ushort4*>(H2 + (size_t)p3.x * 40 + c);
        float w0 = __int_as_float(p0.y), w1 = __int_as_float(p1.y);
        float w2 = __int_as_float(p2.y), w3 = __int_as_float(p3.y);
        acc.x += bf2f(v0.x) * w0 + bf2f(v1.x) * w1 + bf2f(v2.x) * w2 + bf2f(v3.x) * w3;
        acc.y += bf2f(v0.y) * w0 + bf2f(v1.y) * w1 + bf2f(v2.y) * w2 + bf2f(v3.y) * w3;
        acc.z += bf2f(v0.z) * w0 + bf2f(v1.z) * w1 + bf2f(v2.z) * w2 + bf2f(v3.z) * w3;
        acc.w += bf2f(v0.w) * w0 + bf2f(v1.w) * w1 + bf2f(v2.w) * w2 + bf2f(v3.w) * w3;
    }
    for (; j < end; ++j) {
        int2 p = csr[j];
        float w = __int_as_float(p.y);
        ushort4 v = *reinterpret_cast<const ushort4*>(H2 + (size_t)p.x * 40 + c);
        acc.x += bf2f(v.x) * w; acc.y += bf2f(v.y) * w;
        acc.z += bf2f(v.z) * w; acc.w += bf2f(v.w) * w;
    }
    float di = dinv[n];
    float sl = di * di;
    ushort4 sv = *reinterpret_cast<const ushort4*>(H2 + (size_t)n * 40 + c);
    float4 bv = *reinterpret_cast<const float4*>(b2 + c);
    float4 r;
    r.x = fmaf(bf2f(sv.x), sl, acc.x + bv.x);
    r.y = fmaf(bf2f(sv.y), sl, acc.y + bv.y);
    r.z = fmaf(bf2f(sv.z), sl, acc.z + bv.z);
    r.w = fmaf(bf2f(sv.w), sl, acc.w + bv.w);
    *reinterpret_cast<float4*>(out + (size_t)n * 40 + c) = r;
}

// ---------------- launch ----------------

extern "C" void kernel_launch(void* const* d_in, const int* in_sizes, int n_in,
                              void* d_out, int out_size, void* d_ws, size_t ws_size,
                              hipStream_t stream) {
    const float* x  = (const float*)d_in[0];
    const int*   ei = (const int*)d_in[1];     // [2, NE]: row0 = src, row1 = dst
    const float* W1 = (const float*)d_in[2];
    const float* b1 = (const float*)d_in[3];
    const float* W2 = (const float*)d_in[4];
    const float* b2 = (const float*)d_in[5];
    float* out = (float*)d_out;

    // workspace layout (4B elements)
    int*      deg_i    = (int*)d_ws;                   // [50048]
    float*    dinv     = (float*)d_ws + 50048;         // [50048]
    int*      offs     = (int*)d_ws + 100096;          // [50048]
    int*      cursor   = (int*)d_ws + 150144;          // [50048] -> ends after csr_fill
    int*      partials = (int*)d_ws + 200192;          // [512]
    int2*     csr      = (int2*)((int*)d_ws + 200704); // [640000] packed {src, norm}
    ushort_t* H1b      = (ushort_t*)((int*)d_ws + 1480704); // NN*128 bf16 = 3.2M ints
    float*    h        = (float*)d_ws + 4680704;       // [6400000]
    ushort_t* H2b      = H1b;                          // alias: H1 dead after gather128

    const int NB = (NN + 255) / 256;                   // 196 scan blocks

    // CSR build
    hipMemsetAsync(deg_i, 0, NN * sizeof(int), stream);
    hist_kernel<<<(NE + 255) / 256, 256, 0, stream>>>(ei + NE, deg_i);
    scan_block<<<NB, 256, 0, stream>>>(deg_i, offs, partials, NN);
    scan_partials<<<1, 256, 0, stream>>>(partials, NB);
    finalize_offsets<<<NB, 256, 0, stream>>>(offs, partials, cursor, deg_i, dinv, NN);
    csr_fill<<<(NE + 255) / 256, 256, 0, stream>>>(ei, dinv, cursor, csr);

    // layer 1
    gemm_k128_bf16out<<<dim3((NN + 63) / 64, 2), 256, 0, stream>>>(x, W1, H1b, NN, 128);
    gather128<<<NN * 32 / 256, 256, 0, stream>>>(offs, cursor, csr, H1b, dinv, b1, h);

    // layer 2
    gemm_k128_bf16out<<<dim3((NN + 63) / 64, 1), 256, 0, stream>>>(h, W2, H2b, NN, 40);
    gather40<<<(NN * 10 + 255) / 256, 256, 0, stream>>>(offs, cursor, csr, H2b, dinv, b2, out);
}